// Round 15
// baseline (148.735 us; speedup 1.0000x reference)
//
#include <hip/hip_runtime.h>
#include <hip/hip_bf16.h>
#include <stdint.h>

#define T_ 4
#define B_ 16
#define C_ 256
#define N_ 1024
#define HEADS_ 8
#define HD_ 32

typedef unsigned long long u64;
typedef unsigned char u8;

__device__ __forceinline__ u64 rf64(u64 v) {
  unsigned lo = __builtin_amdgcn_readfirstlane((unsigned)v);
  unsigned hi = __builtin_amdgcn_readfirstlane((unsigned)(v >> 32));
  return ((u64)hi << 32) | (u64)lo;
}

// ---------- prep: fused weight transpose [c][o] + BN tables ----------
__global__ __launch_bounds__(256) void prep_kernel(
    const float* __restrict__ qw, const float* __restrict__ kw,
    const float* __restrict__ vw, const float* __restrict__ pw,
    const float* __restrict__ qg, const float* __restrict__ qb2,
    const float* __restrict__ qmn, const float* __restrict__ qvr,
    const float* __restrict__ kg, const float* __restrict__ kb2,
    const float* __restrict__ kmn, const float* __restrict__ kvr,
    const float* __restrict__ vg, const float* __restrict__ vb2,
    const float* __restrict__ vmn, const float* __restrict__ vvr,
    const float* __restrict__ pg, const float* __restrict__ pb2,
    const float* __restrict__ pmn, const float* __restrict__ pvr,
    float* __restrict__ wtq, float* __restrict__ wtk,
    float* __restrict__ wtv, float* __restrict__ wtp,
    float* __restrict__ bnt) {
  if (blockIdx.x < 256) {
    int c = blockIdx.x;
    int o = threadIdx.x;
    wtq[c * C_ + o] = qw[o * C_ + c];
    wtk[c * C_ + o] = kw[o * C_ + c];
    wtv[c * C_ + o] = vw[o * C_ + c];
    wtp[c * C_ + o] = pw[o * C_ + c];
  } else {
    int c = threadIdx.x;
    float rs;
    rs = sqrtf(qvr[c] + 1e-5f);
    bnt[0 * C_ + c] = qg[c] / rs;
    bnt[1 * C_ + c] = qb2[c] - qmn[c] * qg[c] / rs;
    rs = sqrtf(kvr[c] + 1e-5f);
    bnt[2 * C_ + c] = kg[c] / rs;
    bnt[3 * C_ + c] = kb2[c] - kmn[c] * kg[c] / rs;
    rs = sqrtf(vvr[c] + 1e-5f);
    bnt[4 * C_ + c] = vg[c] / rs;
    bnt[5 * C_ + c] = vb2[c] - vmn[c] * vg[c] / rs;
    rs = sqrtf(pvr[c] + 1e-5f);
    bnt[6 * C_ + c] = pg[c] / rs;
    bnt[7 * C_ + c] = pb2[c] - pmn[c] * pg[c] / rs;
  }
}

// ---------- P1: FUSED shortcut-LIF + sparse q/k/v conv + BN + LIF ----------
// grid = b(16) x nt(128 tiles of 8 n).
// Phase A: wave w, lane l owns channel c = 64w+l; LIF over t for 8 n's;
//          ballots -> LDS masks (identical math/convention to r14 lif_shortcut).
// Phase B: r9-verbatim walk from LDS masks (rf64-pinned wave-uniform).
// lane l owns out-channels o = 64j + l, j=0..3 (r9 convention).
__global__ __launch_bounds__(256) void qkv_fused(
    const float* __restrict__ x,
    const float* __restrict__ wtq, const float* __restrict__ wtk,
    const float* __restrict__ wtv, const float* __restrict__ bnt,
    float* __restrict__ pkv, u64* __restrict__ qm_out,
    float* __restrict__ vout) {
  int b = blockIdx.x >> 7;
  int nt = blockIdx.x & 127;
  int n0 = nt << 3;
  int tid = threadIdx.x;
  int l = tid & 63, wv = tid >> 6;

  __shared__ u64 lmask[8][4][4];   // [nn][t][wd] 1 KB

  // ---- Phase A: mask build (verified lif_shortcut math, c = 64w + l) ----
  {
    int c = (wv << 6) + l;
    float v[8];
#pragma unroll
    for (int i = 0; i < 8; i++) v[i] = 0.f;
#pragma unroll
    for (int t = 0; t < T_; t++) {
      const float* xp = x + ((((size_t)t * B_ + b) * C_) + c) * N_ + n0;
      float4 xa = *(const float4*)xp;
      float4 xb = *(const float4*)(xp + 4);
      float xv[8] = {xa.x, xa.y, xa.z, xa.w, xb.x, xb.y, xb.z, xb.w};
#pragma unroll
      for (int nn = 0; nn < 8; nn++) {
        float h = v[nn] + (xv[nn] - v[nn]) * 0.5f;   // tau=2 exact halving
        bool s = h >= 1.0f;
        v[nn] = s ? 0.f : h;                         // hard reset, detach
        u64 bal = __ballot(s);
        if (l == (t << 3) + nn) lmask[nn][t][wv] = bal;
      }
    }
  }
  __syncthreads();

  // ---- Phase B: r9-verbatim sparse walk ----
  float qs[4], qsh[4], ks[4], ksh[4], vsc[4], vsh[4];
#pragma unroll
  for (int j = 0; j < 4; j++) {
    int o = (j << 6) + l;
    qs[j]  = bnt[0 * C_ + o]; qsh[j] = bnt[1 * C_ + o];
    ks[j]  = bnt[2 * C_ + o]; ksh[j] = bnt[3 * C_ + o];
    vsc[j] = bnt[4 * C_ + o]; vsh[j] = bnt[5 * C_ + o];
  }
  int cnt[4][4];
#pragma unroll
  for (int t = 0; t < 4; t++)
#pragma unroll
    for (int j = 0; j < 4; j++) cnt[t][j] = 0;

  for (int nn = wv; nn < 8; nn += 4) {
    int n = n0 + nn;
    float aq[4][4], ak[4][4], av[4][4];   // [t][j]
#pragma unroll
    for (int t = 0; t < 4; t++)
#pragma unroll
      for (int j = 0; j < 4; j++) { aq[t][j] = 0.f; ak[t][j] = 0.f; av[t][j] = 0.f; }
#pragma unroll
    for (int t = 0; t < 4; t++) {
#pragma unroll
      for (int wd = 0; wd < 4; wd++) {
        u64 m = rf64(lmask[nn][t][wd]);    // wave-uniform SGPR walk
        while (m) {
          int c = (wd << 6) + __builtin_ctzll(m);
          m &= (m - 1);
          const float* rq = wtq + c * C_;
          const float* rk = wtk + c * C_;
          const float* rv = wtv + c * C_;
#pragma unroll
          for (int j = 0; j < 4; j++) {
            int o = (j << 6) + l;
            aq[t][j] += rq[o];
            ak[t][j] += rk[o];
            av[t][j] += rv[o];
          }
        }
      }
    }
    // BN + LIF scan over t (verified math)
#pragma unroll
    for (int j = 0; j < 4; j++) {
      int o = (j << 6) + l;
      float vq = 0.f, vk = 0.f, vv = 0.f;
#pragma unroll
      for (int t = 0; t < 4; t++) {
        float pq = aq[t][j] * qs[j] + qsh[j];
        float pk = ak[t][j] * ks[j] + ksh[j];
        float pv = av[t][j] * vsc[j] + vsh[j];
        float hq = vq + (pq - vq) * 0.5f;
        float hk = vk + (pk - vk) * 0.5f;
        float hv = vv + (pv - vv) * 0.5f;
        bool sq = hq >= 1.0f; vq = sq ? 0.f : hq;
        bool sk = hk >= 1.0f; vk = sk ? 0.f : hk;
        bool sv = hv >= 1.0f; vv = sv ? 0.f : hv;
        cnt[t][j] += (sk && sv) ? 1 : 0;
        vout[(((size_t)t * B_ + b) * HEADS_ + (o >> 5)) * ((size_t)N_ * HD_) +
             (size_t)n * HD_ + (o & 31)] = sv ? 1.0f : 0.0f;
        u64 bal = __ballot(sq);
        if (l == (t << 2) + j)
          qm_out[((((size_t)t * B_ + b) * N_ + n) << 2) + j] = bal;
      }
    }
  }
  // cross-wave reduction of kv partial counts (deterministic, no atomics)
  __shared__ int scnt[4][4][C_];
#pragma unroll
  for (int t = 0; t < 4; t++)
#pragma unroll
    for (int j = 0; j < 4; j++) scnt[wv][t][(j << 6) + l] = cnt[t][j];
  __syncthreads();
  // coalesced pkv write: layout [t][b][nt][c] -> 1 KB contiguous per t
  for (int idx = tid; idx < 4 * C_; idx += 256) {
    int t = idx >> 8, c = idx & 255;
    int s = scnt[0][t][c] + scnt[1][t][c] + scnt[2][t][c] + scnt[3][t][c];
    pkv[(((size_t)t * B_ + b) * 128 + nt) * C_ + c] = (float)s;
  }
}

// ---------- P2: reduce kv partials + talking-heads LIF (wide, 1024 thr) -----
__global__ __launch_bounds__(1024) void kv_lif_kernel(const float* __restrict__ pkv,
                                                      u64* __restrict__ kvsm) {
  int b = blockIdx.x;
  int tid = threadIdx.x;
  int c = tid & 255, qtr = tid >> 8;
  __shared__ float part[4][4][C_];   // [qtr][t][c]
#pragma unroll
  for (int t = 0; t < 4; t++) {
    const float* p = pkv + ((((size_t)t * B_ + b) * 128) + (qtr << 5)) * C_ + c;
    float s = 0.f;
#pragma unroll
    for (int i = 0; i < 32; i++) s += p[(size_t)i * C_];   // exact ints
    part[qtr][t][c] = s;
  }
  __syncthreads();
  if (tid < 256) {
    int l = c & 63, j = c >> 6;
    float v = 0.f;
#pragma unroll
    for (int t = 0; t < 4; t++) {
      float kv = part[0][t][c] + part[1][t][c] + part[2][t][c] + part[3][t][c];
      float h = v + (kv - v) * 0.5f;
      bool s = h >= 0.5f;
      v = s ? 0.f : h;
      u64 bal = __ballot(s);
      if (l == t) kvsm[((size_t)t * B_ + b) * 4 + j] = bal;
    }
  }
}

// ---------- P3: attn = q & kvs -> sparse proj + bias + BN + identity ----------
__global__ __launch_bounds__(256) void proj_sparse(
    const u64* __restrict__ qm, const u64* __restrict__ kvsm,
    const float* __restrict__ wtp, const float* __restrict__ bnt,
    const float* __restrict__ pbias, const float* __restrict__ x,
    float* __restrict__ out) {
  int tb = blockIdx.x >> 5;         // 64 (t,b) x 32 n-tiles of 32
  int n0 = (blockIdx.x & 31) << 5;
  int t = tb >> 4, b = tb & 15;
  int tid = threadIdx.x;
  int l = tid & 63, w = tid >> 6;
  __shared__ float tile[C_ * 33];
  u64 kvm[4];
#pragma unroll
  for (int wd = 0; wd < 4; wd++) kvm[wd] = kvsm[((size_t)t * B_ + b) * 4 + wd];
  for (int nn = w; nn < 32; nn += 4) {
    int n = n0 + nn;
    float acc[4] = {0.f, 0.f, 0.f, 0.f};
    const u64* mp = qm + ((((size_t)t * B_ + b) * N_ + n) << 2);
#pragma unroll
    for (int wd = 0; wd < 4; wd++) {
      u64 m = mp[wd] & kvm[wd];
      while (m) {
        int c = (wd << 6) + __builtin_ctzll(m);
        m &= (m - 1);
        const float* rp = wtp + c * C_;
#pragma unroll
        for (int j = 0; j < 4; j++) acc[j] += rp[(j << 6) + l];
      }
    }
#pragma unroll
    for (int j = 0; j < 4; j++) tile[((j << 6) + l) * 33 + nn] = acc[j];
  }
  __syncthreads();
  // per-row epilogue, coalesced over n (verified math)
  int col = l & 31;
  int half = l >> 5;
  for (int r = (w << 1) + half; r < C_; r += 8) {
    float val = tile[r * 33 + col];
    float z = (val + pbias[r]) * bnt[6 * C_ + r] + bnt[7 * C_ + r];
    size_t xi = (((size_t)t * B_ + b) * C_ + r) * N_ + n0 + col;
    out[xi] = z + x[xi];
  }
}

// ---------- diagnostic: if ws too small, zero the output ----------
__global__ __launch_bounds__(256) void fill_zero_f32(float* p, size_t n) {
  size_t i = (size_t)blockIdx.x * 256 + threadIdx.x;
  if (i < n) p[i] = 0.0f;
}

extern "C" void kernel_launch(void* const* d_in, const int* in_sizes, int n_in,
                              void* d_out, int out_size, void* d_ws, size_t ws_size,
                              hipStream_t stream) {
  const float* x  = (const float*)d_in[0];
  const float* qw = (const float*)d_in[1];
  const float* qg = (const float*)d_in[2];
  const float* qb = (const float*)d_in[3];
  const float* qm = (const float*)d_in[4];
  const float* qv = (const float*)d_in[5];
  const float* kw = (const float*)d_in[6];
  const float* kg = (const float*)d_in[7];
  const float* kb = (const float*)d_in[8];
  const float* km = (const float*)d_in[9];
  const float* kv = (const float*)d_in[10];
  const float* vw = (const float*)d_in[11];
  const float* vg = (const float*)d_in[12];
  const float* vb2 = (const float*)d_in[13];
  const float* vm = (const float*)d_in[14];
  const float* vv = (const float*)d_in[15];
  const float* pw = (const float*)d_in[16];
  const float* pbias = (const float*)d_in[17];
  const float* pg = (const float*)d_in[18];
  const float* pb = (const float*)d_in[19];
  const float* pm = (const float*)d_in[20];
  const float* pv = (const float*)d_in[21];

  const size_t needed = 11544576ull;
  if (ws_size < needed) {
    size_t n = (size_t)out_size;
    fill_zero_f32<<<(unsigned)((n + 255) / 256), 256, 0, stream>>>(
        (float*)d_out, n);
    return;
  }

  char* ws = (char*)d_ws;
  float* wtq = (float*)(ws + 0);         // 256 KB [c][o]
  float* wtk = (float*)(ws + 262144);    // 256 KB
  float* wtv = (float*)(ws + 524288);    // 256 KB
  float* wtp = (float*)(ws + 786432);    // 256 KB
  float* bnt = (float*)(ws + 1048576);   // 8 KB
  u64*   qmm = (u64*)  (ws + 1056768);   // 2 MB  [site][4 words], c = 64j+l
  float* pkv = (float*)(ws + 3153920);   // 8 MB  [t][b][nt(128)][c]
  u64*   kvsm = (u64*) (ws + 11542528);  // 2 KB  [t][b][4 words]

  float* out  = (float*)d_out;
  float* vout = out + (size_t)T_ * B_ * C_ * N_;

  prep_kernel<<<257, 256, 0, stream>>>(qw, kw, vw, pw,
                                       qg, qb, qm, qv, kg, kb, km, kv,
                                       vg, vb2, vm, vv, pg, pb, pm, pv,
                                       wtq, wtk, wtv, wtp, bnt);
  qkv_fused<<<2048, 256, 0, stream>>>(x, wtq, wtk, wtv, bnt, pkv, qmm, vout);
  kv_lif_kernel<<<16, 1024, 0, stream>>>(pkv, kvsm);
  proj_sparse<<<2048, 256, 0, stream>>>(qmm, kvsm, wtp, bnt, pbias, x, out);
}

// Round 16
// 142.331 us; speedup vs baseline: 1.0450x; 1.0450x over previous
//
#include <hip/hip_runtime.h>
#include <hip/hip_bf16.h>
#include <stdint.h>

#define T_ 4
#define B_ 16
#define C_ 256
#define N_ 1024
#define HEADS_ 8
#define HD_ 32

typedef unsigned long long u64;
typedef unsigned char u8;

// ---------- prep: fused weight transpose [c][o] + BN tables ----------
__global__ __launch_bounds__(256) void prep_kernel(
    const float* __restrict__ qw, const float* __restrict__ kw,
    const float* __restrict__ vw, const float* __restrict__ pw,
    const float* __restrict__ qg, const float* __restrict__ qb2,
    const float* __restrict__ qmn, const float* __restrict__ qvr,
    const float* __restrict__ kg, const float* __restrict__ kb2,
    const float* __restrict__ kmn, const float* __restrict__ kvr,
    const float* __restrict__ vg, const float* __restrict__ vb2,
    const float* __restrict__ vmn, const float* __restrict__ vvr,
    const float* __restrict__ pg, const float* __restrict__ pb2,
    const float* __restrict__ pmn, const float* __restrict__ pvr,
    float* __restrict__ wtq, float* __restrict__ wtk,
    float* __restrict__ wtv, float* __restrict__ wtp,
    float* __restrict__ bnt) {
  if (blockIdx.x < 256) {
    int c = blockIdx.x;
    int o = threadIdx.x;
    wtq[c * C_ + o] = qw[o * C_ + c];
    wtk[c * C_ + o] = kw[o * C_ + c];
    wtv[c * C_ + o] = vw[o * C_ + c];
    wtp[c * C_ + o] = pw[o * C_ + c];
  } else {
    int c = threadIdx.x;
    float rs;
    rs = sqrtf(qvr[c] + 1e-5f);
    bnt[0 * C_ + c] = qg[c] / rs;
    bnt[1 * C_ + c] = qb2[c] - qmn[c] * qg[c] / rs;
    rs = sqrtf(kvr[c] + 1e-5f);
    bnt[2 * C_ + c] = kg[c] / rs;
    bnt[3 * C_ + c] = kb2[c] - kmn[c] * kg[c] / rs;
    rs = sqrtf(vvr[c] + 1e-5f);
    bnt[4 * C_ + c] = vg[c] / rs;
    bnt[5 * C_ + c] = vb2[c] - vmn[c] * vg[c] / rs;
    rs = sqrtf(pvr[c] + 1e-5f);
    bnt[6 * C_ + c] = pg[c] / rs;
    bnt[7 * C_ + c] = pb2[c] - pmn[c] * pg[c] / rs;
  }
}

// ---------- P0: shortcut LIF -> xs bitmasks [site][4 words], c = 64w + l ----
__global__ __launch_bounds__(256) void lif_shortcut(const float* __restrict__ x,
                                                    u64* __restrict__ xsm) {
  int b = blockIdx.x >> 5;          // 32 n-tiles of 32
  int n0 = (blockIdx.x & 31) << 5;
  int tid = threadIdx.x;
  int l = tid & 63, w = tid >> 6;
  __shared__ float tile[C_ * 33];
  float v[32];
#pragma unroll
  for (int i = 0; i < 32; i++) v[i] = 0.f;
  int c = (w << 6) + l;             // this thread's channel
  for (int t = 0; t < T_; t++) {
    __syncthreads();
    const float* xp = x + (((size_t)t * B_ + b) * C_) * N_ + n0;
    for (int idx = tid; idx < C_ * 32; idx += 256) {
      int cc = idx >> 5, nn = idx & 31;
      tile[cc * 33 + nn] = xp[(size_t)cc * N_ + nn];
    }
    __syncthreads();
#pragma unroll
    for (int nn = 0; nn < 32; nn++) {
      float xv = tile[c * 33 + nn];
      float h = v[nn] + (xv - v[nn]) * 0.5f;   // tau=2 exact halving
      bool s = h >= 1.0f;
      v[nn] = s ? 0.f : h;                     // hard reset, detach
      u64 bal = __ballot(s);
      if (l == nn) xsm[(((size_t)t * B_ + b) * N_ + n0 + nn) * 4 + w] = bal;
    }
  }
}

// ---------- P1: sparse q/k/v conv + BN + LIF (r9-verbatim best) ----------
// grid = b(16) x nt(128 tiles of 8 n); wave wv owns sites nn = wv, wv+4.
// lane l owns out-channels o = 64j + l, j=0..3.
__global__ __launch_bounds__(256) void qkv_sparse(
    const u64* __restrict__ xsm,
    const float* __restrict__ wtq, const float* __restrict__ wtk,
    const float* __restrict__ wtv, const float* __restrict__ bnt,
    float* __restrict__ pkv, u64* __restrict__ qm_out,
    float* __restrict__ vout) {
  int b = blockIdx.x >> 7;
  int nt = blockIdx.x & 127;
  int n0 = nt << 3;
  int tid = threadIdx.x;
  int l = tid & 63, wv = tid >> 6;
  float qs[4], qsh[4], ks[4], ksh[4], vsc[4], vsh[4];
#pragma unroll
  for (int j = 0; j < 4; j++) {
    int o = (j << 6) + l;
    qs[j]  = bnt[0 * C_ + o]; qsh[j] = bnt[1 * C_ + o];
    ks[j]  = bnt[2 * C_ + o]; ksh[j] = bnt[3 * C_ + o];
    vsc[j] = bnt[4 * C_ + o]; vsh[j] = bnt[5 * C_ + o];
  }
  int cnt[4][4];
#pragma unroll
  for (int t = 0; t < 4; t++)
#pragma unroll
    for (int j = 0; j < 4; j++) cnt[t][j] = 0;

  for (int nn = wv; nn < 8; nn += 4) {
    int n = n0 + nn;
    float aq[4][4], ak[4][4], av[4][4];   // [t][j]
#pragma unroll
    for (int t = 0; t < 4; t++)
#pragma unroll
      for (int j = 0; j < 4; j++) { aq[t][j] = 0.f; ak[t][j] = 0.f; av[t][j] = 0.f; }
#pragma unroll
    for (int t = 0; t < 4; t++) {
      const u64* mp = xsm + ((((size_t)t * B_ + b) * N_ + n) << 2);
#pragma unroll
      for (int wd = 0; wd < 4; wd++) {
        u64 m = mp[wd];                    // wave-uniform, register walk
        while (m) {
          int c = (wd << 6) + __builtin_ctzll(m);
          m &= (m - 1);
          const float* rq = wtq + c * C_;
          const float* rk = wtk + c * C_;
          const float* rv = wtv + c * C_;
#pragma unroll
          for (int j = 0; j < 4; j++) {
            int o = (j << 6) + l;
            aq[t][j] += rq[o];
            ak[t][j] += rk[o];
            av[t][j] += rv[o];
          }
        }
      }
    }
    // BN + LIF scan over t (verified math)
#pragma unroll
    for (int j = 0; j < 4; j++) {
      int o = (j << 6) + l;
      float vq = 0.f, vk = 0.f, vv = 0.f;
#pragma unroll
      for (int t = 0; t < 4; t++) {
        float pq = aq[t][j] * qs[j] + qsh[j];
        float pk = ak[t][j] * ks[j] + ksh[j];
        float pv = av[t][j] * vsc[j] + vsh[j];
        float hq = vq + (pq - vq) * 0.5f;
        float hk = vk + (pk - vk) * 0.5f;
        float hv = vv + (pv - vv) * 0.5f;
        bool sq = hq >= 1.0f; vq = sq ? 0.f : hq;
        bool sk = hk >= 1.0f; vk = sk ? 0.f : hk;
        bool sv = hv >= 1.0f; vv = sv ? 0.f : hv;
        cnt[t][j] += (sk && sv) ? 1 : 0;
        vout[(((size_t)t * B_ + b) * HEADS_ + (o >> 5)) * ((size_t)N_ * HD_) +
             (size_t)n * HD_ + (o & 31)] = sv ? 1.0f : 0.0f;
        u64 bal = __ballot(sq);
        if (l == (t << 2) + j)
          qm_out[((((size_t)t * B_ + b) * N_ + n) << 2) + j] = bal;
      }
    }
  }
  // cross-wave reduction of kv partial counts (deterministic, no atomics)
  __shared__ int scnt[4][4][C_];
#pragma unroll
  for (int t = 0; t < 4; t++)
#pragma unroll
    for (int j = 0; j < 4; j++) scnt[wv][t][(j << 6) + l] = cnt[t][j];
  __syncthreads();
  // coalesced pkv write: layout [t][b][nt][c] -> 1 KB contiguous per t
  for (int idx = tid; idx < 4 * C_; idx += 256) {
    int t = idx >> 8, c = idx & 255;
    int s = scnt[0][t][c] + scnt[1][t][c] + scnt[2][t][c] + scnt[3][t][c];
    pkv[(((size_t)t * B_ + b) * 128 + nt) * C_ + c] = (float)s;
  }
}

// ---------- P2: reduce kv partials + talking-heads LIF (wide, 1024 thr) -----
// block b; thread = (qtr, c); quarter-sums in LDS (exact ints, order-free),
// then waves 0-3 (c = 64j + l) do the LIF scan + ballots (r9 kvsm layout).
__global__ __launch_bounds__(1024) void kv_lif_kernel(const float* __restrict__ pkv,
                                                      u64* __restrict__ kvsm) {
  int b = blockIdx.x;
  int tid = threadIdx.x;
  int c = tid & 255, qtr = tid >> 8;
  __shared__ float part[4][4][C_];   // [qtr][t][c]
#pragma unroll
  for (int t = 0; t < 4; t++) {
    const float* p = pkv + ((((size_t)t * B_ + b) * 128) + (qtr << 5)) * C_ + c;
    float s = 0.f;
#pragma unroll
    for (int i = 0; i < 32; i++) s += p[(size_t)i * C_];   // exact ints
    part[qtr][t][c] = s;
  }
  __syncthreads();
  if (tid < 256) {
    int l = c & 63, j = c >> 6;
    float v = 0.f;
#pragma unroll
    for (int t = 0; t < 4; t++) {
      float kv = part[0][t][c] + part[1][t][c] + part[2][t][c] + part[3][t][c];
      float h = v + (kv - v) * 0.5f;
      bool s = h >= 0.5f;
      v = s ? 0.f : h;
      u64 bal = __ballot(s);
      if (l == t) kvsm[((size_t)t * B_ + b) * 4 + j] = bal;
    }
  }
}

// ---------- P3: attn = q & kvs -> sparse proj + bias + BN + identity ----------
__global__ __launch_bounds__(256) void proj_sparse(
    const u64* __restrict__ qm, const u64* __restrict__ kvsm,
    const float* __restrict__ wtp, const float* __restrict__ bnt,
    const float* __restrict__ pbias, const float* __restrict__ x,
    float* __restrict__ out) {
  int tb = blockIdx.x >> 5;         // 64 (t,b) x 32 n-tiles of 32
  int n0 = (blockIdx.x & 31) << 5;
  int t = tb >> 4, b = tb & 15;
  int tid = threadIdx.x;
  int l = tid & 63, w = tid >> 6;
  __shared__ float tile[C_ * 33];
  u64 kvm[4];
#pragma unroll
  for (int wd = 0; wd < 4; wd++) kvm[wd] = kvsm[((size_t)t * B_ + b) * 4 + wd];
  for (int nn = w; nn < 32; nn += 4) {
    int n = n0 + nn;
    float acc[4] = {0.f, 0.f, 0.f, 0.f};
    const u64* mp = qm + ((((size_t)t * B_ + b) * N_ + n) << 2);
#pragma unroll
    for (int wd = 0; wd < 4; wd++) {
      u64 m = mp[wd] & kvm[wd];
      while (m) {
        int c = (wd << 6) + __builtin_ctzll(m);
        m &= (m - 1);
        const float* rp = wtp + c * C_;
#pragma unroll
        for (int j = 0; j < 4; j++) acc[j] += rp[(j << 6) + l];
      }
    }
#pragma unroll
    for (int j = 0; j < 4; j++) tile[((j << 6) + l) * 33 + nn] = acc[j];
  }
  __syncthreads();
  // per-row epilogue, coalesced over n (verified math)
  int col = l & 31;
  int half = l >> 5;
  for (int r = (w << 1) + half; r < C_; r += 8) {
    float val = tile[r * 33 + col];
    float z = (val + pbias[r]) * bnt[6 * C_ + r] + bnt[7 * C_ + r];
    size_t xi = (((size_t)t * B_ + b) * C_ + r) * N_ + n0 + col;
    out[xi] = z + x[xi];
  }
}

// ---------- diagnostic: if ws too small, zero the output ----------
__global__ __launch_bounds__(256) void fill_zero_f32(float* p, size_t n) {
  size_t i = (size_t)blockIdx.x * 256 + threadIdx.x;
  if (i < n) p[i] = 0.0f;
}

extern "C" void kernel_launch(void* const* d_in, const int* in_sizes, int n_in,
                              void* d_out, int out_size, void* d_ws, size_t ws_size,
                              hipStream_t stream) {
  const float* x  = (const float*)d_in[0];
  const float* qw = (const float*)d_in[1];
  const float* qg = (const float*)d_in[2];
  const float* qb = (const float*)d_in[3];
  const float* qm = (const float*)d_in[4];
  const float* qv = (const float*)d_in[5];
  const float* kw = (const float*)d_in[6];
  const float* kg = (const float*)d_in[7];
  const float* kb = (const float*)d_in[8];
  const float* km = (const float*)d_in[9];
  const float* kv = (const float*)d_in[10];
  const float* vw = (const float*)d_in[11];
  const float* vg = (const float*)d_in[12];
  const float* vb2 = (const float*)d_in[13];
  const float* vm = (const float*)d_in[14];
  const float* vv = (const float*)d_in[15];
  const float* pw = (const float*)d_in[16];
  const float* pbias = (const float*)d_in[17];
  const float* pg = (const float*)d_in[18];
  const float* pb = (const float*)d_in[19];
  const float* pm = (const float*)d_in[20];
  const float* pv = (const float*)d_in[21];

  const size_t needed = 13641728ull;
  if (ws_size < needed) {
    size_t n = (size_t)out_size;
    fill_zero_f32<<<(unsigned)((n + 255) / 256), 256, 0, stream>>>(
        (float*)d_out, n);
    return;
  }

  char* ws = (char*)d_ws;
  float* wtq = (float*)(ws + 0);         // 256 KB [c][o]
  float* wtk = (float*)(ws + 262144);    // 256 KB
  float* wtv = (float*)(ws + 524288);    // 256 KB
  float* wtp = (float*)(ws + 786432);    // 256 KB
  float* bnt = (float*)(ws + 1048576);   // 8 KB
  u64*   xsm = (u64*)  (ws + 1056768);   // 2 MB  [site][4 words], c = 64w+l
  u64*   qmm = (u64*)  (ws + 3153920);   // 2 MB  [site][4 words], c = 64j+l
  float* pkv = (float*)(ws + 5251072);   // 8 MB  [t][b][nt(128)][c]
  u64*   kvsm = (u64*) (ws + 13639680);  // 2 KB  [t][b][4 words]

  float* out  = (float*)d_out;
  float* vout = out + (size_t)T_ * B_ * C_ * N_;

  prep_kernel<<<257, 256, 0, stream>>>(qw, kw, vw, pw,
                                       qg, qb, qm, qv, kg, kb, km, kv,
                                       vg, vb2, vm, vv, pg, pb, pm, pv,
                                       wtq, wtk, wtv, wtp, bnt);
  lif_shortcut<<<512, 256, 0, stream>>>(x, xsm);
  qkv_sparse<<<2048, 256, 0, stream>>>(xsm, wtq, wtk, wtv, bnt, pkv, qmm, vout);
  kv_lif_kernel<<<16, 1024, 0, stream>>>(pkv, kvsm);
  proj_sparse<<<2048, 256, 0, stream>>>(qmm, kvsm, wtp, bnt, pbias, x, out);
}